// Round 12
// baseline (371.442 us; speedup 1.0000x reference)
//
#include <hip/hip_runtime.h>

#define T_DIM 128
#define B_DIM 2048
#define D_DIM 1024
#define KW 8
#define NCOL (B_DIM * 16)      // 32768 columns

// Per double-buffer half (32768 B):
//   A region [0,16384):      [kc<2][jh<2][mloc<256][16B]
//   X region [16384,32768):  [kc<2][jh<2][col<256][16B]
#define BUFB 32768
#define CHUNKS 32              // K chunks of 32

typedef _Float16 f16x8 __attribute__((ext_vector_type(8)));
typedef float    f32x16 __attribute__((ext_vector_type(16)));

static __device__ __forceinline__ int imax(int a, int b) { return a > b ? a : b; }
static __device__ __forceinline__ int imin(int a, int b) { return a < b ? a : b; }

__device__ __forceinline__ f16x8 cvt2(float4 u, float4 v) {
    f16x8 h;
    h[0] = (_Float16)u.x; h[1] = (_Float16)u.y;
    h[2] = (_Float16)u.z; h[3] = (_Float16)u.w;
    h[4] = (_Float16)v.x; h[5] = (_Float16)v.y;
    h[6] = (_Float16)v.z; h[7] = (_Float16)v.w;
    return h;
}

// ---------------------------------------------------------------------------
// Kernel 0: W1 fp32 [m][k] -> W1g: 128 slabs (c<32 x mt<4) of 16KB, each the
// exact linear LDS A-image [kc<2][jh<2][mloc<256][8 f16]:
//   element = W1[mt*256 + mloc][c*32 + kc*16 + jh*8 + j]
// ---------------------------------------------------------------------------
__global__ void k_cvt_w1(const float* __restrict__ W1, _Float16* __restrict__ W1g) {
    int i  = blockIdx.x * 256 + threadIdx.x;   // 65536 threads
    int m  = i >> 6;           // 0..1023
    int r  = i & 63;
    int c  = r >> 1;           // chunk 0..31
    int kc = r & 1;
    const float* src = W1 + (size_t)m * D_DIM + c * 32 + kc * 16;
    float4 x0 = *(const float4*)(src);
    float4 x1 = *(const float4*)(src + 4);
    float4 x2 = *(const float4*)(src + 8);
    float4 x3 = *(const float4*)(src + 12);
    _Float16* dst = W1g + (size_t)(c * 4 + (m >> 8)) * 8192 + kc * 4096 + (m & 255) * 8;
    *(f16x8*)(dst)        = cvt2(x0, x1);   // jh = 0
    *(f16x8*)(dst + 2048) = cvt2(x2, x3);   // jh = 1
}

// ---------------------------------------------------------------------------
// Kernel 1 (fused gather + 256x256 GEMM + tanh/W2 epilogue), r4-style loop:
// grid = 512 blocks = 4 mt x 128 cg; bijective XCD swizzle keeps the 4
// mt-siblings of a cg on one XCD (shared X stream in its L2).
// 512 threads, 8 waves (mg<2 x ng<4), wave-tile 128m x 64n, acc[4][2].
// Per 32-k chunk: reg-stage A (2 uint4/thread from linear W1g image) and
// X (4 float4/thread gathered fp32) for chunk c+1; compute chunk c from
// LDS (2 kc-steps x 8 MFMA per wave); write staged into other buffer; one
// barrier. Plain loops only — no macros/setprio/global_load_lds (rounds
// 8-10: that structure spilled acc to scratch, VGPR=104, ~900us).
// ---------------------------------------------------------------------------
__launch_bounds__(512, 2)
__global__ void k_gemm(const float* __restrict__ hctx,
                       const int*   __restrict__ offsets,
                       const int*   __restrict__ stc,
                       const int*   __restrict__ sep_l,
                       const _Float16* __restrict__ W1g,
                       const float* __restrict__ W2,
                       float* __restrict__ s_part /* [4][NCOL] */) {
    __shared__ __align__(16) char lds[2 * BUFB];   // 64 KB exactly

    int orig = blockIdx.x;
    int wgid = (orig & 7) * 64 + (orig >> 3);   // bijective: 512 % 8 == 0
    int mt   = wgid & 3;
    int cg   = wgid >> 2;      // 0..127

    int tid  = threadIdx.x;
    int wid  = tid >> 6;
    int lane = tid & 63;
    int lr   = lane & 31;
    int hi   = lane >> 5;
    int mg   = wid >> 2;       // 0..1
    int ng   = wid & 3;        // 0..3

    // ---- X gather setup: thread owns (col, kh) ----
    int s_col = tid & 255;
    int kh    = tid >> 8;      // 0..1: which kc-plane of the chunk
    int col = cg * 256 + s_col;
    int b   = col >> 4;
    int li  = col & 15;
    int off = offsets[b];
    int sep = sep_l[b];
    int st  = stc[b];
    bool in1 = (off <= sep);
    int start = in1 ? imax(off - KW, 0)   : imax(off - KW, sep + 1);
    int end   = in1 ? imin(off + KW, sep) : imin(off + KW, st);
    int idx = start + li;
    bool valid = (idx < end);
    int tc = imin(imax(idx, 0), T_DIM - 1);
    const float* hrow = hctx + ((size_t)tc * B_DIM + b) * D_DIM + kh * 16;
    int xw0 = 16384 + (kh * 2) * 4096 + s_col * 16;   // jh=0; jh=1 at +4096

    // ---- A staging: thread copies 16B at t16 and 8192+t16 (lane-stride-16,
    // conflict-free ds_write_b128; coalesced 1KB/wave global loads) ----
    const char* wg = (const char*)W1g;
    int t16 = tid * 16;

    // ---- frag read offsets ----
    int a_off = mg * 2048 + lr * 16;            // + (kc*2+hi)*4096 + f*512
    int x_off = 16384 + ng * 1024 + lr * 16;    // + (kc*2+hi)*4096 + nf*512

    f32x16 acc[4][2];
#pragma unroll
    for (int f = 0; f < 4; ++f)
#pragma unroll
        for (int nf = 0; nf < 2; ++nf)
#pragma unroll
            for (int i = 0; i < 16; ++i) acc[f][nf][i] = 0.f;

    float4 z = {0.f, 0.f, 0.f, 0.f};

    // ---- prologue: stage chunk 0 into buf0 ----
    {
        const char* sl = wg + (size_t)(0 * 4 + mt) * 16384;
        uint4 a0 = *(const uint4*)(sl + t16);
        uint4 a1 = *(const uint4*)(sl + 8192 + t16);
        float4 x0 = valid ? *(const float4*)(hrow)      : z;
        float4 x1 = valid ? *(const float4*)(hrow + 4)  : z;
        float4 x2 = valid ? *(const float4*)(hrow + 8)  : z;
        float4 x3 = valid ? *(const float4*)(hrow + 12) : z;
        *(uint4*)(lds + t16)        = a0;
        *(uint4*)(lds + 8192 + t16) = a1;
        *(f16x8*)(lds + xw0)        = cvt2(x0, x1);
        *(f16x8*)(lds + xw0 + 4096) = cvt2(x2, x3);
    }
    __syncthreads();

    // ---- main loop: 32 chunks of 32 k ----
    for (int c = 0; c < CHUNKS; ++c) {
        const char* cbuf = lds + (c & 1) * BUFB;

        // stage chunk c+1 into registers (issued before compute)
        uint4 an0, an1;
        float4 xn0, xn1, xn2, xn3;
        if (c < CHUNKS - 1) {
            const char* sl = wg + (size_t)((c + 1) * 4 + mt) * 16384;
            an0 = *(const uint4*)(sl + t16);
            an1 = *(const uint4*)(sl + 8192 + t16);
            const float* sp = hrow + (c + 1) * 32;
            xn0 = valid ? *(const float4*)(sp)      : z;
            xn1 = valid ? *(const float4*)(sp + 4)  : z;
            xn2 = valid ? *(const float4*)(sp + 8)  : z;
            xn3 = valid ? *(const float4*)(sp + 12) : z;
        }

        // compute chunk c: 2 kc-steps x 8 MFMA
#pragma unroll
        for (int kc = 0; kc < 2; ++kc) {
            const char* pa = cbuf + (kc * 2 + hi) * 4096 + a_off;
            const char* px = cbuf + (kc * 2 + hi) * 4096 + x_off;
            f16x8 af0 = *(const f16x8*)(pa);
            f16x8 af1 = *(const f16x8*)(pa + 512);
            f16x8 af2 = *(const f16x8*)(pa + 1024);
            f16x8 af3 = *(const f16x8*)(pa + 1536);
            f16x8 xf0 = *(const f16x8*)(px);
            f16x8 xf1 = *(const f16x8*)(px + 512);
            acc[0][0] = __builtin_amdgcn_mfma_f32_32x32x16_f16(af0, xf0, acc[0][0], 0, 0, 0);
            acc[1][0] = __builtin_amdgcn_mfma_f32_32x32x16_f16(af1, xf0, acc[1][0], 0, 0, 0);
            acc[2][0] = __builtin_amdgcn_mfma_f32_32x32x16_f16(af2, xf0, acc[2][0], 0, 0, 0);
            acc[3][0] = __builtin_amdgcn_mfma_f32_32x32x16_f16(af3, xf0, acc[3][0], 0, 0, 0);
            acc[0][1] = __builtin_amdgcn_mfma_f32_32x32x16_f16(af0, xf1, acc[0][1], 0, 0, 0);
            acc[1][1] = __builtin_amdgcn_mfma_f32_32x32x16_f16(af1, xf1, acc[1][1], 0, 0, 0);
            acc[2][1] = __builtin_amdgcn_mfma_f32_32x32x16_f16(af2, xf1, acc[2][1], 0, 0, 0);
            acc[3][1] = __builtin_amdgcn_mfma_f32_32x32x16_f16(af3, xf1, acc[3][1], 0, 0, 0);
        }

        // write staged chunk into the other buffer
        if (c < CHUNKS - 1) {
            char* nbuf = lds + ((c + 1) & 1) * BUFB;
            *(uint4*)(nbuf + t16)        = an0;
            *(uint4*)(nbuf + 8192 + t16) = an1;
            *(f16x8*)(nbuf + xw0)        = cvt2(xn0, xn1);
            *(f16x8*)(nbuf + xw0 + 4096) = cvt2(xn2, xn3);
        }
        __syncthreads();
    }

    // ---- epilogue: tanh + W2 dot ----
    // D layout (32x32): col = lane&31, row = (r&3) + 8*(r>>2) + 4*(lane>>5)
    float sp0 = 0.f, sp1 = 0.f;
#pragma unroll
    for (int f = 0; f < 4; ++f) {
#pragma unroll
        for (int rg = 0; rg < 4; ++rg) {
            int mbase = mt * 256 + mg * 128 + f * 32 + rg * 8 + hi * 4;
            float4 w2v = *(const float4*)(W2 + mbase);
            float w2a[4] = {w2v.x, w2v.y, w2v.z, w2v.w};
#pragma unroll
            for (int j = 0; j < 4; ++j) {
                float w2 = w2a[j];
                {
                    float xv = acc[f][0][rg * 4 + j];
                    float e = __expf(2.f * xv);
                    sp0 += w2 * (1.f - 2.f / (e + 1.f));
                }
                {
                    float xv = acc[f][1][rg * 4 + j];
                    float e = __expf(2.f * xv);
                    sp1 += w2 * (1.f - 2.f / (e + 1.f));
                }
            }
        }
    }
    sp0 += __shfl_xor(sp0, 32, 64);   // fold hi halves (same col)
    sp1 += __shfl_xor(sp1, 32, 64);

    float* red = (float*)lds;          // alias buf0 (loop done; barrier below)
    if (hi == 0) {
        red[wid * 64 + lr]      = sp0;   // col-local = ng*64 + lr
        red[wid * 64 + 32 + lr] = sp1;   // col-local = ng*64 + 32 + lr
    }
    __syncthreads();
    if (tid < 256) {
        int ngc = tid >> 6;
        int cl  = tid & 63;
        float s = red[ngc * 64 + cl] + red[(4 + ngc) * 64 + cl];
        s_part[(size_t)mt * NCOL + cg * 256 + tid] = s;
    }
}

// ---------------------------------------------------------------------------
// Kernel 2: sum 4 mt-partials, per-l max and sum-exp over B (softmax stats).
// ---------------------------------------------------------------------------
__global__ void k_smax1(const float* __restrict__ s_part,
                        float* __restrict__ s_raw,
                        float* __restrict__ lstats /* [32]: 16 max, 16 sum */) {
    int l = blockIdx.x;
    int t = threadIdx.x;
    int lane = t & 63, wid = t >> 6;

    float v[8];
    float mx = -__builtin_inff();
#pragma unroll
    for (int i = 0; i < 8; ++i) {
        int b = i * 256 + t;
        int id = b * 16 + l;
        float x = s_part[id] + s_part[NCOL + id] +
                  s_part[2 * NCOL + id] + s_part[3 * NCOL + id];
        v[i] = x;
        s_raw[id] = x;
        mx = fmaxf(mx, x);
    }
#pragma unroll
    for (int d = 1; d < 64; d <<= 1) mx = fmaxf(mx, __shfl_xor(mx, d, 64));
    __shared__ float rm[4];
    if (lane == 0) rm[wid] = mx;
    __syncthreads();
    mx = fmaxf(fmaxf(rm[0], rm[1]), fmaxf(rm[2], rm[3]));

    float se = 0.f;
#pragma unroll
    for (int i = 0; i < 8; ++i) se += __expf(v[i] - mx);
#pragma unroll
    for (int d = 1; d < 64; d <<= 1) se += __shfl_xor(se, d, 64);
    __shared__ float rs[4];
    if (lane == 0) rs[wid] = se;
    __syncthreads();
    if (t == 0) {
        lstats[l]      = mx;
        lstats[16 + l] = rs[0] + rs[1] + rs[2] + rs[3];
    }
}

// ---------------------------------------------------------------------------
// Kernel 3: masked softmax over l + weighted gather-sum to output.
// ---------------------------------------------------------------------------
__global__ void k_out(const float* __restrict__ hctx,
                      const int*   __restrict__ offsets,
                      const int*   __restrict__ stc,
                      const int*   __restrict__ sep_l,
                      const float* __restrict__ s_raw,
                      const float* __restrict__ lstats,
                      float* __restrict__ out) {
    int b = blockIdx.x;
    int t = threadIdx.x;

    int off = offsets[b];
    int sep = sep_l[b];
    int st  = stc[b];
    bool in1 = (off <= sep);
    int start = in1 ? imax(off - KW, 0)   : imax(off - KW, sep + 1);
    int end   = in1 ? imin(off + KW, sep) : imin(off + KW, st);

    float p[16];
    float m2 = -__builtin_inff();
#pragma unroll
    for (int l = 0; l < 16; ++l) {
        bool valid = (start + l) < end;
        float s = s_raw[b * 16 + l];
        float pl = __expf(s - lstats[l]) / lstats[16 + l];
        p[l] = valid ? pl : -__builtin_inff();
        m2 = fmaxf(m2, p[l]);
    }
    float q[16];
    float qs = 0.f;
#pragma unroll
    for (int l = 0; l < 16; ++l) {
        float e = __expf(p[l] - m2);   // exp(-inf) = 0 for invalid
        q[l] = e;
        qs += e;
    }
    float rqs = 1.f / qs;

    float4 acc = {0.f, 0.f, 0.f, 0.f};
#pragma unroll
    for (int l = 0; l < 16; ++l) {
        float wl = q[l] * rqs;
        if (wl > 0.f) {
            int tr = imin(imax(start + l, 0), T_DIM - 1);
            float4 x = *((const float4*)(hctx + ((size_t)tr * B_DIM + b) * D_DIM) + t);
            acc.x += wl * x.x; acc.y += wl * x.y;
            acc.z += wl * x.z; acc.w += wl * x.w;
        }
    }
    *((float4*)(out + (size_t)b * D_DIM) + t) = acc;
}

// ---------------------------------------------------------------------------
extern "C" void kernel_launch(void* const* d_in, const int* in_sizes, int n_in,
                              void* d_out, int out_size, void* d_ws, size_t ws_size,
                              hipStream_t stream) {
    const float* hctx    = (const float*)d_in[0];
    const int*   offsets = (const int*)d_in[1];
    const int*   stc     = (const int*)d_in[2];
    const int*   sep     = (const int*)d_in[3];
    // d_in[4] = no_local (unused by reference)
    const float* W1      = (const float*)d_in[5];
    const float* W2      = (const float*)d_in[6];
    float* out = (float*)d_out;

    char* ws = (char*)d_ws;
    _Float16* W1g    = (_Float16*)ws;                              // 2 MB
    float*    s_part = (float*)(ws + (2u << 20));                  // 512 KB
    float*    s_raw  = (float*)(ws + (2u << 20) + (512u << 10));   // 128 KB
    float*    lstats = (float*)(ws + (2u << 20) + (640u << 10));

    hipLaunchKernelGGL(k_cvt_w1, dim3(256),  dim3(256), 0, stream, W1, W1g);
    hipLaunchKernelGGL(k_gemm,   dim3(512),  dim3(512), 0, stream,
                       hctx, offsets, stc, sep, W1g, W2, s_part);
    hipLaunchKernelGGL(k_smax1,  dim3(16),   dim3(256), 0, stream,
                       s_part, s_raw, lstats);
    hipLaunchKernelGGL(k_out,    dim3(2048), dim3(256), 0, stream,
                       hctx, offsets, stc, sep, s_raw, lstats, out);
}

// Round 13
// 332.249 us; speedup vs baseline: 1.1180x; 1.1180x over previous
//
#include <hip/hip_runtime.h>

#define T_DIM 128
#define B_DIM 2048
#define D_DIM 1024
#define KW 8
#define NCOL (B_DIM * 16)      // 32768 columns

// X LDS buffer: [kcL<8][jh<2][col<128][16B] = 32768 B per buffer
#define XBUF 32768

typedef _Float16 f16x8 __attribute__((ext_vector_type(8)));
typedef float    f32x16 __attribute__((ext_vector_type(16)));

static __device__ __forceinline__ int imax(int a, int b) { return a > b ? a : b; }
static __device__ __forceinline__ int imin(int a, int b) { return a < b ? a : b; }

__device__ __forceinline__ f16x8 cvt2(float4 u, float4 v) {
    f16x8 h;
    h[0] = (_Float16)u.x; h[1] = (_Float16)u.y;
    h[2] = (_Float16)u.z; h[3] = (_Float16)u.w;
    h[4] = (_Float16)v.x; h[5] = (_Float16)v.y;
    h[6] = (_Float16)v.z; h[7] = (_Float16)v.w;
    return h;
}

// ---------------------------------------------------------------------------
// Kernel 0: W1 fp32 [m][k] -> fp16 fragment-interleaved W1f[kc][m][j]
//   W1f[(kc*1024 + m)*16 + j] = W1[m*1024 + kc*16 + j],  kc<64, j<16
// (identical to the round-4/5 version)
// ---------------------------------------------------------------------------
__global__ void k_cvt_w1(const float* __restrict__ W1, _Float16* __restrict__ W1f) {
    int i  = blockIdx.x * 256 + threadIdx.x;   // 65536 threads
    int m  = i >> 6;
    int kc = i & 63;
    const float* src = W1 + (size_t)m * D_DIM + kc * 16;
    float4 x0 = *(const float4*)(src);
    float4 x1 = *(const float4*)(src + 4);
    float4 x2 = *(const float4*)(src + 8);
    float4 x3 = *(const float4*)(src + 12);
    _Float16* dst = W1f + ((size_t)kc * 1024 + m) * 16;
    *(f16x8*)(dst)     = cvt2(x0, x1);
    *(f16x8*)(dst + 8) = cvt2(x2, x3);
}

// ---------------------------------------------------------------------------
// Kernel 1 (fused gather + GEMM + tanh/W2 epilogue) — r4/r5 loop mechanics
// with a 64m x 128n wave-tile (acc[2][4], 128 VGPR) to halve the A-through-L1
// flow per kc-step (the identified co-limiter of the r5 kernel).
// Block: 512 m (8 waves x 64m) x 128 cols; BK=128 chunks, X dbuf in LDS,
// staging split in two 4-float4 halves (reg pressure); A depth-2 reg
// prefetch from L2-resident W1f. grid = 512: bijective XCD swizzle puts the
// two mt-twins of each cg on one XCD (shared X stream in its L2).
// Writes s_part[mt][col] = partial over 512 m.
// ---------------------------------------------------------------------------
__launch_bounds__(512, 2)
__global__ void k_gemm(const float* __restrict__ hctx,
                       const int*   __restrict__ offsets,
                       const int*   __restrict__ stc,
                       const int*   __restrict__ sep_l,
                       const _Float16* __restrict__ W1f,
                       const float* __restrict__ W2,
                       float* __restrict__ s_part /* [2][NCOL] */) {
    __shared__ __align__(16) char ldsx[2 * XBUF];
    __shared__ float red[8][128];

    int orig = blockIdx.x;
    int wgid = (orig & 7) * 64 + (orig >> 3);   // bijective: 512 % 8 == 0
    int mt   = wgid & 1;
    int cg   = wgid >> 1;      // 0..255 (128-col groups)

    int tid  = threadIdx.x;
    int wid  = tid >> 6;       // 0..7 : m-slice [wid*64, wid*64+64)
    int lane = tid & 63;
    int lr   = lane & 31;
    int hi   = lane >> 5;

    // ---- X staging: thread owns (col, ks) ; ks = 32-k span of the chunk ----
    int s_col = tid & 127;
    int ks    = tid >> 7;      // 0..3
    int col = cg * 128 + s_col;
    int b   = col >> 4;
    int li  = col & 15;
    int off = offsets[b];
    int sep = sep_l[b];
    int st  = stc[b];
    bool in1 = (off <= sep);
    int start = in1 ? imax(off - KW, 0)   : imax(off - KW, sep + 1);
    int end   = in1 ? imin(off + KW, sep) : imin(off + KW, st);
    int idx = start + li;
    bool valid = (idx < end);
    int tc = imin(imax(idx, 0), T_DIM - 1);
    const float* sbase = hctx + ((size_t)tc * B_DIM + b) * D_DIM + ks * 32;
    int xw = (2 * ks) * 4096 + s_col * 16;   // plane 2ks, jh0; jh1 +2048; plane 2ks+1 +4096

    // ---- A geometry: frag (f<2, kc) at ap + kc*16384 + f*512 (f16 units) ----
    const _Float16* ap = W1f + (size_t)(mt * 512 + wid * 64 + lr) * 16 + hi * 8;

    // ---- X frag read: (kcL, nf<4) at kcL*4096 + x_roff + nf*512 (bytes) ----
    int x_roff = hi * 2048 + lr * 16;

    f32x16 acc[2][4];
#pragma unroll
    for (int f = 0; f < 2; ++f)
#pragma unroll
        for (int nf = 0; nf < 4; ++nf)
#pragma unroll
            for (int i = 0; i < 16; ++i) acc[f][nf][i] = 0.f;

    float4 z = {0.f, 0.f, 0.f, 0.f};

    // ---- prologue: stage chunk 0 into buf0 ----
    {
#pragma unroll
        for (int h = 0; h < 2; ++h) {
            const float* sp = sbase + h * 16;
            float4 x0 = valid ? *(const float4*)(sp)      : z;
            float4 x1 = valid ? *(const float4*)(sp + 4)  : z;
            float4 x2 = valid ? *(const float4*)(sp + 8)  : z;
            float4 x3 = valid ? *(const float4*)(sp + 12) : z;
            *(f16x8*)(ldsx + xw + h * 4096)        = cvt2(x0, x1);
            *(f16x8*)(ldsx + xw + h * 4096 + 2048) = cvt2(x2, x3);
        }
    }

    // A pipeline: a0 = a(0), a1 = a(1)
    f16x8 a0[2], a1[2];
#pragma unroll
    for (int f = 0; f < 2; ++f) a0[f] = *(const f16x8*)(ap + f * 512);
#pragma unroll
    for (int f = 0; f < 2; ++f) a1[f] = *(const f16x8*)(ap + 16384 + f * 512);

    __syncthreads();

    // ---- main loop: 8 chunks of 128 k (8 kc-planes each) ----
    for (int c = 0; c < 8; ++c) {
        int bufr = (c & 1) * XBUF;
        char* nxt = ldsx + (((c + 1) & 1) * XBUF);
        bool pre = (c < 7);
        const float* sp = sbase + (c + 1) * 128;

        float4 xa0, xa1, xa2, xa3;
        if (pre) {                       // half A: k-sub [0,16) of our span
            xa0 = valid ? *(const float4*)(sp)      : z;
            xa1 = valid ? *(const float4*)(sp + 4)  : z;
            xa2 = valid ? *(const float4*)(sp + 8)  : z;
            xa3 = valid ? *(const float4*)(sp + 12) : z;
        }

#pragma unroll
        for (int kcL = 0; kcL < 4; ++kcL) {
            int kc = c * 8 + kcL;
            int ka = (kc + 2) & 63;
            f16x8 a2[2];
            a2[0] = *(const f16x8*)(ap + (size_t)ka * 16384);
            a2[1] = *(const f16x8*)(ap + (size_t)ka * 16384 + 512);
            const char* px = ldsx + bufr + kcL * 4096 + x_roff;
            f16x8 xf0 = *(const f16x8*)(px);
            f16x8 xf1 = *(const f16x8*)(px + 512);
            f16x8 xf2 = *(const f16x8*)(px + 1024);
            f16x8 xf3 = *(const f16x8*)(px + 1536);
            acc[0][0] = __builtin_amdgcn_mfma_f32_32x32x16_f16(a0[0], xf0, acc[0][0], 0, 0, 0);
            acc[1][0] = __builtin_amdgcn_mfma_f32_32x32x16_f16(a0[1], xf0, acc[1][0], 0, 0, 0);
            acc[0][1] = __builtin_amdgcn_mfma_f32_32x32x16_f16(a0[0], xf1, acc[0][1], 0, 0, 0);
            acc[1][1] = __builtin_amdgcn_mfma_f32_32x32x16_f16(a0[1], xf1, acc[1][1], 0, 0, 0);
            acc[0][2] = __builtin_amdgcn_mfma_f32_32x32x16_f16(a0[0], xf2, acc[0][2], 0, 0, 0);
            acc[1][2] = __builtin_amdgcn_mfma_f32_32x32x16_f16(a0[1], xf2, acc[1][2], 0, 0, 0);
            acc[0][3] = __builtin_amdgcn_mfma_f32_32x32x16_f16(a0[0], xf3, acc[0][3], 0, 0, 0);
            acc[1][3] = __builtin_amdgcn_mfma_f32_32x32x16_f16(a0[1], xf3, acc[1][3], 0, 0, 0);
            a0[0] = a1[0]; a0[1] = a1[1];
            a1[0] = a2[0]; a1[1] = a2[1];
        }

        float4 xb0, xb1, xb2, xb3;
        if (pre) {                       // write half A; issue half B loads
            *(f16x8*)(nxt + xw)        = cvt2(xa0, xa1);
            *(f16x8*)(nxt + xw + 2048) = cvt2(xa2, xa3);
            xb0 = valid ? *(const float4*)(sp + 16) : z;
            xb1 = valid ? *(const float4*)(sp + 20) : z;
            xb2 = valid ? *(const float4*)(sp + 24) : z;
            xb3 = valid ? *(const float4*)(sp + 28) : z;
        }

#pragma unroll
        for (int kcL = 4; kcL < 8; ++kcL) {
            int kc = c * 8 + kcL;
            int ka = (kc + 2) & 63;
            f16x8 a2[2];
            a2[0] = *(const f16x8*)(ap + (size_t)ka * 16384);
            a2[1] = *(const f16x8*)(ap + (size_t)ka * 16384 + 512);
            const char* px = ldsx + bufr + kcL * 4096 + x_roff;
            f16x8 xf0 = *(const f16x8*)(px);
            f16x8 xf1 = *(const f16x8*)(px + 512);
            f16x8 xf2 = *(const f16x8*)(px + 1024);
            f16x8 xf3 = *(const f16x8*)(px + 1536);
            acc[0][0] = __builtin_amdgcn_mfma_f32_32x32x16_f16(a0[0], xf0, acc[0][0], 0, 0, 0);
            acc[1][0] = __builtin_amdgcn_mfma_f32_32x32x16_f16(a0[1], xf0, acc[1][0], 0, 0, 0);
            acc[0][1] = __builtin_amdgcn_mfma_f32_32x32x16_f16(a0[0], xf1, acc[0][1], 0, 0, 0);
            acc[1][1] = __builtin_amdgcn_mfma_f32_32x32x16_f16(a0[1], xf1, acc[1][1], 0, 0, 0);
            acc[0][2] = __builtin_amdgcn_mfma_f32_32x32x16_f16(a0[0], xf2, acc[0][2], 0, 0, 0);
            acc[1][2] = __builtin_amdgcn_mfma_f32_32x32x16_f16(a0[1], xf2, acc[1][2], 0, 0, 0);
            acc[0][3] = __builtin_amdgcn_mfma_f32_32x32x16_f16(a0[0], xf3, acc[0][3], 0, 0, 0);
            acc[1][3] = __builtin_amdgcn_mfma_f32_32x32x16_f16(a0[1], xf3, acc[1][3], 0, 0, 0);
            a0[0] = a1[0]; a0[1] = a1[1];
            a1[0] = a2[0]; a1[1] = a2[1];
        }

        if (pre) {                       // write half B
            *(f16x8*)(nxt + xw + 4096)        = cvt2(xb0, xb1);
            *(f16x8*)(nxt + xw + 4096 + 2048) = cvt2(xb2, xb3);
        }
        __syncthreads();
    }

    // ---- epilogue: tanh + W2 dot ----
    // D layout (32x32): col = lane&31, row = (r&3) + 8*(r>>2) + 4*(lane>>5)
    float sp_[4] = {0.f, 0.f, 0.f, 0.f};
#pragma unroll
    for (int f = 0; f < 2; ++f) {
#pragma unroll
        for (int rg = 0; rg < 4; ++rg) {
            int mbase = mt * 512 + wid * 64 + f * 32 + rg * 8 + hi * 4;
            float4 w2v = *(const float4*)(W2 + mbase);
            float w2a[4] = {w2v.x, w2v.y, w2v.z, w2v.w};
#pragma unroll
            for (int j = 0; j < 4; ++j) {
                float w2 = w2a[j];
#pragma unroll
                for (int nf = 0; nf < 4; ++nf) {
                    float xv = acc[f][nf][rg * 4 + j];
                    float e = __expf(2.f * xv);
                    sp_[nf] += w2 * (1.f - 2.f / (e + 1.f));
                }
            }
        }
    }
#pragma unroll
    for (int nf = 0; nf < 4; ++nf) sp_[nf] += __shfl_xor(sp_[nf], 32, 64);

    if (hi == 0) {
#pragma unroll
        for (int nf = 0; nf < 4; ++nf) red[wid][nf * 32 + lr] = sp_[nf];
    }
    __syncthreads();
    if (tid < 128) {
        float s = 0.f;
#pragma unroll
        for (int w = 0; w < 8; ++w) s += red[w][tid];
        s_part[(size_t)mt * NCOL + cg * 128 + tid] = s;
    }
}

// ---------------------------------------------------------------------------
// Kernel 2: sum mt-partials, per-l max and sum-exp over B (softmax stats).
// ---------------------------------------------------------------------------
__global__ void k_smax1(const float* __restrict__ s_part,
                        float* __restrict__ s_raw,
                        float* __restrict__ lstats /* [32]: 16 max, 16 sum */) {
    int l = blockIdx.x;
    int t = threadIdx.x;
    int lane = t & 63, wid = t >> 6;

    float v[8];
    float mx = -__builtin_inff();
#pragma unroll
    for (int i = 0; i < 8; ++i) {
        int b = i * 256 + t;
        int id = b * 16 + l;
        float x = s_part[id] + s_part[NCOL + id];
        v[i] = x;
        s_raw[id] = x;
        mx = fmaxf(mx, x);
    }
#pragma unroll
    for (int d = 1; d < 64; d <<= 1) mx = fmaxf(mx, __shfl_xor(mx, d, 64));
    __shared__ float rm[4];
    if (lane == 0) rm[wid] = mx;
    __syncthreads();
    mx = fmaxf(fmaxf(rm[0], rm[1]), fmaxf(rm[2], rm[3]));

    float se = 0.f;
#pragma unroll
    for (int i = 0; i < 8; ++i) se += __expf(v[i] - mx);
#pragma unroll
    for (int d = 1; d < 64; d <<= 1) se += __shfl_xor(se, d, 64);
    __shared__ float rs[4];
    if (lane == 0) rs[wid] = se;
    __syncthreads();
    if (t == 0) {
        lstats[l]      = mx;
        lstats[16 + l] = rs[0] + rs[1] + rs[2] + rs[3];
    }
}

// ---------------------------------------------------------------------------
// Kernel 3: masked softmax over l + weighted gather-sum to output.
// ---------------------------------------------------------------------------
__global__ void k_out(const float* __restrict__ hctx,
                      const int*   __restrict__ offsets,
                      const int*   __restrict__ stc,
                      const int*   __restrict__ sep_l,
                      const float* __restrict__ s_raw,
                      const float* __restrict__ lstats,
                      float* __restrict__ out) {
    int b = blockIdx.x;
    int t = threadIdx.x;

    int off = offsets[b];
    int sep = sep_l[b];
    int st  = stc[b];
    bool in1 = (off <= sep);
    int start = in1 ? imax(off - KW, 0)   : imax(off - KW, sep + 1);
    int end   = in1 ? imin(off + KW, sep) : imin(off + KW, st);

    float p[16];
    float m2 = -__builtin_inff();
#pragma unroll
    for (int l = 0; l < 16; ++l) {
        bool valid = (start + l) < end;
        float s = s_raw[b * 16 + l];
        float pl = __expf(s - lstats[l]) / lstats[16 + l];
        p[l] = valid ? pl : -__builtin_inff();
        m2 = fmaxf(m2, p[l]);
    }
    float q[16];
    float qs = 0.f;
#pragma unroll
    for (int l = 0; l < 16; ++l) {
        float e = __expf(p[l] - m2);   // exp(-inf) = 0 for invalid
        q[l] = e;
        qs += e;
    }
    float rqs = 1.f / qs;

    float4 acc = {0.f, 0.f, 0.f, 0.f};
#pragma unroll
    for (int l = 0; l < 16; ++l) {
        float wl = q[l] * rqs;
        if (wl > 0.f) {
            int tr = imin(imax(start + l, 0), T_DIM - 1);
            float4 x = *((const float4*)(hctx + ((size_t)tr * B_DIM + b) * D_DIM) + t);
            acc.x += wl * x.x; acc.y += wl * x.y;
            acc.z += wl * x.z; acc.w += wl * x.w;
        }
    }
    *((float4*)(out + (size_t)b * D_DIM) + t) = acc;
}

// ---------------------------------------------------------------------------
extern "C" void kernel_launch(void* const* d_in, const int* in_sizes, int n_in,
                              void* d_out, int out_size, void* d_ws, size_t ws_size,
                              hipStream_t stream) {
    const float* hctx    = (const float*)d_in[0];
    const int*   offsets = (const int*)d_in[1];
    const int*   stc     = (const int*)d_in[2];
    const int*   sep     = (const int*)d_in[3];
    // d_in[4] = no_local (unused by reference)
    const float* W1      = (const float*)d_in[5];
    const float* W2      = (const float*)d_in[6];
    float* out = (float*)d_out;

    char* ws = (char*)d_ws;
    _Float16* W1f    = (_Float16*)ws;                              // 2 MB
    float*    s_part = (float*)(ws + (2u << 20));                  // 256 KB
    float*    s_raw  = (float*)(ws + (2u << 20) + (256u << 10));   // 128 KB
    float*    lstats = (float*)(ws + (2u << 20) + (384u << 10));

    hipLaunchKernelGGL(k_cvt_w1, dim3(256),  dim3(256), 0, stream, W1, W1f);
    hipLaunchKernelGGL(k_gemm,   dim3(512),  dim3(512), 0, stream,
                       hctx, offsets, stc, sep, W1f, W2, s_part);
    hipLaunchKernelGGL(k_smax1,  dim3(16),   dim3(256), 0, stream,
                       s_part, s_raw, lstats);
    hipLaunchKernelGGL(k_out,    dim3(2048), dim3(256), 0, stream,
                       hctx, offsets, stc, sep, s_raw, lstats, out);
}